// Round 4
// baseline (640.455 us; speedup 1.0000x reference)
//
#include <hip/hip_runtime.h>
#include <hip/hip_bf16.h>

// Problem constants: B=64, T=2048, D=256, U=256 (fp32 in/out)
#define BB 64
#define TT 2048
#define DD 256
#define UU 256
#define MM (BB*TT)          // 131072 GEMM rows
#define NN (3*UU)           // 768 fused output cols (z,r,h)
#define PLANE ((size_t)BB*TT*UU)   // 33554432 elements per projection plane

typedef _Float16 half8 __attribute__((ext_vector_type(8)));
typedef _Float16 half4 __attribute__((ext_vector_type(4)));
typedef float floatx4 __attribute__((ext_vector_type(4)));

// ---------------- fast math helpers ----------------
__device__ inline float fexp2(float x){
#if __has_builtin(__builtin_amdgcn_exp2f)
  return __builtin_amdgcn_exp2f(x);
#else
  return exp2f(x);
#endif
}
__device__ inline float frcp(float x){
#if __has_builtin(__builtin_amdgcn_rcpf)
  return __builtin_amdgcn_rcpf(x);
#else
  return 1.0f/x;
#endif
}
// tanh(a) = 1 - 2/(exp2(2*log2e*a)+1)  (saturates correctly at +-inf)
__device__ inline float ftanh(float a){
  const float TWO_L2E = 2.8853900817779268f;
  return 1.0f - 2.0f*frcp(fexp2(TWO_L2E*a) + 1.0f);
}
__device__ inline float fsigmoid(float a){
  const float L2E = 1.4426950408889634f;
  return frcp(1.0f + fexp2(-L2E*a));
}

// ---------------- kernel 0: weights -> fused transposed f16 [N=768][K=256] ----------------
__global__ __launch_bounds__(256) void prep_kernel(const float* __restrict__ kz,
                                                   const float* __restrict__ kr,
                                                   const float* __restrict__ kh,
                                                   _Float16* __restrict__ K16T){
  int o = blockIdx.x*256 + threadIdx.x;     // 0..196607
  int n = o >> 8;                            // fused col: p*256+u
  int k = o & 255;                           // d
  int p = n >> 8;
  int u = n & 255;
  const float* w = (p==0) ? kz : ((p==1) ? kr : kh);
  K16T[o] = (_Float16)w[k*UU + u];
}

// ---------------- kernel 1: GEMM  -> P[p][b*U+u][t] (t-major, f16) ----------------
#define BM 128
#define BN 128
#define BK 32
// Conflict-free LDS layout (global_load_lds-compatible):
//   As = smem[0..4095]      : [kq][m][8]  (kq = k-octet 0..3, m = 0..127)
//   Bs = smem[4096..8191]   : [kq][n][8]
// Frag reads are 256B-contiguous per 16-lane group -> 0 bank conflicts
// (round-2 Bs [n][k] row stride 64B was an 8-way conflict: 9.4M cyc/dispatch).
// Epilogue: direct scattered half4 stores (round-2 proven; round-3 LDS-staged
// transpose epilogue cost +53us from extra barriers + wave divergence).
#define AS_OFF 0
#define BS_OFF 4096

__global__ __launch_bounds__(256) void gemm_kernel(const float* __restrict__ X,
                                                   const _Float16* __restrict__ K16T,
                                                   const float* __restrict__ bz,
                                                   const float* __restrict__ br,
                                                   const float* __restrict__ bh,
                                                   _Float16* __restrict__ P){
  __shared__ __align__(16) _Float16 smem[8192];   // 16384 B
  const int tid = threadIdx.x;

  // ---- bijective XCD-aware remap (6144 blocks = 8 XCDs x 768) ----
  // XCD k owns M-panels [k*128, k*128+128); the 6 N-tiles of a panel are
  // temporally adjacent so the 128KB A-panel is fetched once per L2, and
  // the whole 384KB K16T stays L2-resident. (FETCH 397MB -> 68MB)
  const int l   = blockIdx.y*6 + blockIdx.x;   // hw linear id (x fastest)
  const int xcd = l & 7;
  const int idx = l >> 3;                      // 0..767 within xcd
  const int pnl = idx / 6;                     // 0..127: M panel within chunk
  const int by  = xcd*128 + pnl;               // logical M tile
  const int bx  = idx - pnl*6;                 // logical N tile 0..5
  const int rowBase = by*BM;
  const int nBase   = bx*BN;

  const int wave = tid >> 6, lane = tid & 63;
  const int wm = wave & 1, wn = wave >> 1;     // 2x2 wave grid, each 64x64
  const int lrow = lane & 15, lkq = lane >> 4; // frag row / k-octet

  floatx4 acc[4][4] = {};

  // A staging: thread = (row, k-half). Each thread loads one 64B run of X,
  // writes two [kq][m] cells -> ds_write lanes are 16B-consecutive (0-conflict).
  const int arow = tid & 127;
  const int asel = tid >> 7;                   // 0/1: k-cols asel*16..+15
  const float* aptr = X + (size_t)(rowBase + arow)*DD + asel*16;
  _Float16* aw0 = smem + AS_OFF + ((asel*2 + 0)*128 + arow)*8;
  _Float16* aw1 = smem + AS_OFF + ((asel*2 + 1)*128 + arow)*8;

  // B staging: chunk c=tid -> (kq=tid>>7, n=tid&127); c=tid+256 -> kq+2 (=+16 halves)
  const _Float16* bsrc = K16T + (size_t)(nBase + (tid & 127))*DD + (tid >> 7)*8;

  for (int k0 = 0; k0 < DD; k0 += BK) {
    __syncthreads();   // protect LDS from previous iteration's readers
    // --- A tile: fp32 loads first; the cvt's vmcnt wait leaves the two B
    //     global_load_lds (issued after) in flight until the barrier ---
    floatx4 a0 = *(const floatx4*)(aptr + k0);
    floatx4 a1 = *(const floatx4*)(aptr + k0 + 4);
    floatx4 a2 = *(const floatx4*)(aptr + k0 + 8);
    floatx4 a3 = *(const floatx4*)(aptr + k0 + 12);
    // --- B tile: async global->LDS (f16, 2 x 16B per thread, lane-linear dst) ---
    __builtin_amdgcn_global_load_lds(
        (const __attribute__((address_space(1))) void*)(bsrc + k0),
        (__attribute__((address_space(3))) void*)(smem + BS_OFF + tid*8),
        16, 0, 0);
    __builtin_amdgcn_global_load_lds(
        (const __attribute__((address_space(1))) void*)(bsrc + k0 + 16),
        (__attribute__((address_space(3))) void*)(smem + BS_OFF + (tid + 256)*8),
        16, 0, 0);
    // --- cvt + LDS write for A ---
    half8 pk0, pk1;
    #pragma unroll
    for (int q = 0; q < 4; q++){
      pk0[q]   = (_Float16)a0[q];
      pk0[4+q] = (_Float16)a1[q];
      pk1[q]   = (_Float16)a2[q];
      pk1[4+q] = (_Float16)a3[q];
    }
    *(half8*)aw0 = pk0;
    *(half8*)aw1 = pk1;
    __syncthreads();
    // --- fragments + MFMA (BK=32 == one K step) ---
    half8 af[4], bf[4];
    #pragma unroll
    for (int i = 0; i < 4; i++)
      af[i] = *(const half8*)&smem[AS_OFF + (lkq*128 + wm*64 + i*16 + lrow)*8];
    #pragma unroll
    for (int j = 0; j < 4; j++)
      bf[j] = *(const half8*)&smem[BS_OFF + (lkq*128 + wn*64 + j*16 + lrow)*8];
    #pragma unroll
    for (int i = 0; i < 4; i++)
      #pragma unroll
      for (int j = 0; j < 4; j++)
        acc[i][j] = __builtin_amdgcn_mfma_f32_16x16x32_f16(af[i], bf[j], acc[i][j], 0, 0, 0);
  }

  // --- epilogue: add bias, packed half4 store into t-major plane p ---
  // P[p][b*256 + u][t], t = (m % 2048). r=0..3 of each acc reg are t-consecutive.
  const int p = bx >> 1;                // plane (z/r/h); BN=128 never crosses planes
  const int ub = (bx & 1) * 128;        // u base within plane
  const float* bias = (p==0) ? bz : ((p==1) ? br : bh);
  _Float16* Pp = P + (size_t)p * PLANE;
  const int bidx = rowBase >> 11;                 // batch index (uniform per block)
  const int t0 = (rowBase & 2047) + wm*64 + lkq*4;
  #pragma unroll
  for (int j = 0; j < 4; j++){
    int col = ub + wn*64 + j*16 + lrow;           // u  (C/D: col = lane&15)
    float bv = bias[col];
    _Float16* rowp = Pp + (size_t)(bidx*UU + col)*TT + t0;
    #pragma unroll
    for (int i = 0; i < 4; i++){
      half4 v;
      #pragma unroll
      for (int r = 0; r < 4; r++)
        v[r] = (_Float16)(acc[i][j][r] + bv);     // row = quad*4+reg => t0 + i*16 + r
      *(half4*)(rowp + i*16) = v;
    }
  }
}

// ---------------- kernel 2: time scan, TWO chains per lane (ILP-2) ----------------
// 16384 chains = 256 waves = 1 wave/SIMD chip-wide: pure latency-bound regime
// (~205 cy/step exposed vs ~44 cy issue). Two independent chains per lane
// interleave their ~60cy dependent chains -> stalls filled by the sibling chain.
// 128 blocks x 64 lanes; lane handles chains c0 = g*128+l and c1 = c0+64
// (same batch row; both store/load streams stay wave-coalesced).
#define PF 16          // timesteps per chunk
#define NBUF 2         // register ring depth (2 bufs x 2 chains: ring = 96 VGPR)
__global__ __launch_bounds__(64) void scan_kernel(const _Float16* __restrict__ P,
                                                  const float* __restrict__ mz,
                                                  const float* __restrict__ mr,
                                                  float* __restrict__ out){
  const int lid = threadIdx.x;
  const int g   = blockIdx.x;                 // 0..127
  const int c0  = g*128 + lid;                // chain A
  const int c1  = c0 + 64;                    // chain B (same b: 128 | 256)
  const int b   = c0 >> 8;
  const int u0  = c0 & 255;
  const int u1  = u0 + 64;
  const half8* pz0 = (const half8*)(P + (size_t)c0*TT);
  const half8* pr0 = (const half8*)(P + PLANE + (size_t)c0*TT);
  const half8* ph0 = (const half8*)(P + 2*PLANE + (size_t)c0*TT);
  const half8* pz1 = (const half8*)(P + (size_t)c1*TT);
  const half8* pr1 = (const half8*)(P + PLANE + (size_t)c1*TT);
  const half8* ph1 = (const half8*)(P + 2*PLANE + (size_t)c1*TT);
  float* po0 = out + (size_t)b*(TT*UU) + u0;
  float* po1 = po0 + 64;
  const float vmz0 = mz[u0], vmr0 = mr[u0];
  const float vmz1 = mz[u1], vmr1 = mr[u1];
  float h0 = 0.0f, h1 = 0.0f;

  half8 qz[NBUF][2][2], qr[NBUF][2][2], qh[NBUF][2][2];  // [buf][chain][half]

#define LOADC(buf, c) do { \
    qz[buf][0][0] = pz0[(c)*2]; qz[buf][0][1] = pz0[(c)*2+1]; \
    qr[buf][0][0] = pr0[(c)*2]; qr[buf][0][1] = pr0[(c)*2+1]; \
    qh[buf][0][0] = ph0[(c)*2]; qh[buf][0][1] = ph0[(c)*2+1]; \
    qz[buf][1][0] = pz1[(c)*2]; qz[buf][1][1] = pz1[(c)*2+1]; \
    qr[buf][1][0] = pr1[(c)*2]; qr[buf][1][1] = pr1[(c)*2+1]; \
    qh[buf][1][0] = ph1[(c)*2]; qh[buf][1][1] = ph1[(c)*2+1]; \
  } while(0)

#define PROC(buf, c) do { \
    _Pragma("unroll") \
    for (int i = 0; i < PF; i++){ \
      float xz0 = (float)qz[buf][0][i>>3][i&7]; \
      float xr0 = (float)qr[buf][0][i>>3][i&7]; \
      float xh0 = (float)qh[buf][0][i>>3][i&7]; \
      float xz1 = (float)qz[buf][1][i>>3][i&7]; \
      float xr1 = (float)qr[buf][1][i>>3][i&7]; \
      float xh1 = (float)qh[buf][1][i>>3][i&7]; \
      float r0  = ftanh(xr0 + h0*vmr0) + 1.0f; \
      float r1  = ftanh(xr1 + h1*vmr1) + 1.0f; \
      float z0  = fsigmoid(xz0 + h0*vmz0); \
      float z1  = fsigmoid(xz1 + h1*vmz1); \
      float hh0 = ftanh(xh0 + r0*h0); \
      float hh1 = ftanh(xh1 + r1*h1); \
      h0 = (1.0f - z0)*hh0 + z0*h0; \
      h1 = (1.0f - z1)*hh1 + z1*h1; \
      po0[(size_t)((c)*PF + i)*UU] = h0; \
      po1[(size_t)((c)*PF + i)*UU] = h1; \
    } \
    if ((c) + NBUF < NC) LOADC(buf, (c) + NBUF); \
  } while(0)

  const int NC = TT/PF;   // 128 chunks
  LOADC(0, 0); LOADC(1, 1);
  for (int c = 0; c < NC; c += NBUF){
    PROC(0, c);
    PROC(1, c+1);
  }
#undef LOADC
#undef PROC
}

extern "C" void kernel_launch(void* const* d_in, const int* in_sizes, int n_in,
                              void* d_out, int out_size, void* d_ws, size_t ws_size,
                              hipStream_t stream) {
  (void)in_sizes; (void)n_in; (void)out_size; (void)ws_size;
  const float* x  = (const float*)d_in[0];
  const float* kz = (const float*)d_in[1];
  const float* kr = (const float*)d_in[2];
  const float* kh = (const float*)d_in[3];
  const float* mz = (const float*)d_in[4];
  const float* mr = (const float*)d_in[5];
  const float* bz = (const float*)d_in[6];
  const float* br = (const float*)d_in[7];
  const float* bh = (const float*)d_in[8];
  float* out = (float*)d_out;

  // ws layout: [K16T: 768*256 f16 = 393216 B][P: 3 planes * 33554432 f16 = 201326592 B]
  _Float16* K16T = (_Float16*)d_ws;
  _Float16* P    = (_Float16*)((char*)d_ws + 393216);

  hipLaunchKernelGGL(prep_kernel, dim3(NN*DD/256), dim3(256), 0, stream, kz, kr, kh, K16T);
  hipLaunchKernelGGL(gemm_kernel, dim3(NN/BN, MM/BM), dim3(256), 0, stream,
                     x, K16T, bz, br, bh, P);
  hipLaunchKernelGGL(scan_kernel, dim3(128), dim3(64), 0, stream, P, mz, mr, out);
}

// Round 5
// 474.261 us; speedup vs baseline: 1.3504x; 1.3504x over previous
//
#include <hip/hip_runtime.h>
#include <hip/hip_bf16.h>

// Problem constants: B=64, T=2048, D=256, U=256 (fp32 in/out)
#define BB 64
#define TT 2048
#define DD 256
#define UU 256
#define MM (BB*TT)          // 131072 GEMM rows
#define NN (3*UU)           // 768 fused output cols (z,r,h)
#define PLANE ((size_t)BB*TT*UU)   // 33554432 elements per projection plane

typedef _Float16 half8 __attribute__((ext_vector_type(8)));
typedef _Float16 half4 __attribute__((ext_vector_type(4)));
typedef float floatx4 __attribute__((ext_vector_type(4)));

// ---------------- fast math helpers ----------------
__device__ inline float fexp2(float x){
#if __has_builtin(__builtin_amdgcn_exp2f)
  return __builtin_amdgcn_exp2f(x);
#else
  return exp2f(x);
#endif
}
__device__ inline float frcp(float x){
#if __has_builtin(__builtin_amdgcn_rcpf)
  return __builtin_amdgcn_rcpf(x);
#else
  return 1.0f/x;
#endif
}
// tanh(a) = 1 - 2/(exp2(2*log2e*a)+1)  (saturates correctly at +-inf)
__device__ inline float ftanh(float a){
  const float TWO_L2E = 2.8853900817779268f;
  return 1.0f - 2.0f*frcp(fexp2(TWO_L2E*a) + 1.0f);
}
__device__ inline float fsigmoid(float a){
  const float L2E = 1.4426950408889634f;
  return frcp(1.0f + fexp2(-L2E*a));
}

// ---------------- kernel 0a: weights -> fused transposed f16 [N=768][K=256] ----------------
__global__ __launch_bounds__(256) void prep_kernel(const float* __restrict__ kz,
                                                   const float* __restrict__ kr,
                                                   const float* __restrict__ kh,
                                                   _Float16* __restrict__ K16T){
  int o = blockIdx.x*256 + threadIdx.x;     // 0..196607
  int n = o >> 8;                            // fused col: p*256+u
  int k = o & 255;                           // d
  int p = n >> 8;
  int u = n & 255;
  const float* w = (p==0) ? kz : ((p==1) ? kr : kh);
  K16T[o] = (_Float16)w[k*UU + u];
}

// ---------------- kernel 0b: X fp32 -> f16 prepass (into d_out used as scratch) ----------------
// Memory-bound: 134MB read + 67MB write ~= 32us. Removes the in-gemm cvt chain:
// gemm A-path becomes pure global_load_lds (no fp32 regs, no vmcnt stall, half the bytes).
__global__ __launch_bounds__(256) void xcvt_kernel(const float* __restrict__ X,
                                                   _Float16* __restrict__ X16){
  const size_t t = (size_t)blockIdx.x*256 + threadIdx.x;   // 1,048,576 threads
  #pragma unroll
  for (int i = 0; i < 8; i++){
    const size_t u = ((size_t)i << 20) + t;  // 16B units, lane-consecutive
    floatx4 v = *(const floatx4*)(X + u*4);
    half4 hv;
    #pragma unroll
    for (int q = 0; q < 4; q++) hv[q] = (_Float16)v[q];
    *(half4*)(X16 + u*4) = hv;
  }
}

// ---------------- kernel 1: GEMM  -> P[p][b*U+u][t] (t-major, f16) ----------------
#define BM 128
#define BN 128
#define BK 32
// LDS: As [m][32] f16 (8KB) + Bs [n][32] f16 (8KB) = 16KB, single-buffered.
// Both tiles staged via global_load_lds, 16B chunks, lane-consecutive addresses:
// each wave-instr touches 16 cache lines (the coalesced minimum). The old A path
// (fp32 loads at 1KB lane stride) was 64 lines/instr + an in-order cvt stall and
// +16 live VGPRs -- the one invariant across rounds 0-4 while gemm sat at 187us.
// acc[4][4] lives in 64 AGPRs (unified file): ~112 regs/lane -> 4 blocks/CU
// (was ~132 -> 3, achieved 2.5). Known 8-way ds_read conflict on [m][k] layout
// is proven off-critical-path here (round 2/3: removing it changed nothing).

__global__ __launch_bounds__(256) void gemm_kernel(const _Float16* __restrict__ X16,
                                                   const _Float16* __restrict__ K16T,
                                                   const float* __restrict__ bz,
                                                   const float* __restrict__ br,
                                                   const float* __restrict__ bh,
                                                   _Float16* __restrict__ P){
  __shared__ __align__(16) _Float16 As[BM*BK];   // 8192 B
  __shared__ __align__(16) _Float16 Bs[BN*BK];   // 8192 B
  const int tid = threadIdx.x;

  // ---- bijective XCD-aware remap (6144 blocks = 8 XCDs x 768) ----
  // XCD k owns M-panels [k*128, k*128+128); the 6 N-tiles of a panel are
  // temporally adjacent so the A-panel is fetched once per L2 and the whole
  // 384KB K16T stays L2-resident. (FETCH 397MB -> 68MB, rounds 1-4)
  const int l   = blockIdx.y*6 + blockIdx.x;   // hw linear id (x fastest)
  const int xcd = l & 7;
  const int idx = l >> 3;                      // 0..767 within xcd
  const int pnl = idx / 6;                     // 0..127: M panel within chunk
  const int by  = xcd*128 + pnl;               // logical M tile
  const int bx  = idx - pnl*6;                 // logical N tile 0..5
  const int rowBase = by*BM;
  const int nBase   = bx*BN;

  const int wave = tid >> 6, lane = tid & 63;
  const int wm = wave & 1, wn = wave >> 1;     // 2x2 wave grid, each 64x64
  const int lrow = lane & 15, lkq = lane >> 4; // frag row / k-octet

  floatx4 acc[4][4] = {};

  // Staging: chunk c covers (row = c>>2, k-octet = c&3); thread owns c=tid and
  // c=tid+256 for each of A and B. LDS dst is c-linear (wave-uniform + lane*16).
  const _Float16* aSrc0 = X16 + (size_t)(rowBase + (tid >> 2))*DD + (tid & 3)*8;
  const _Float16* aSrc1 = aSrc0 + (size_t)64*DD;   // c=256+tid -> row+64
  const _Float16* bSrc0 = K16T + (size_t)(nBase + (tid >> 2))*DD + (tid & 3)*8;
  const _Float16* bSrc1 = bSrc0 + (size_t)64*DD;

  for (int k0 = 0; k0 < DD; k0 += BK) {
    __syncthreads();   // previous iteration's readers done before overwrite
    __builtin_amdgcn_global_load_lds(
        (const __attribute__((address_space(1))) void*)(aSrc0 + k0),
        (__attribute__((address_space(3))) void*)(As + tid*8), 16, 0, 0);
    __builtin_amdgcn_global_load_lds(
        (const __attribute__((address_space(1))) void*)(aSrc1 + k0),
        (__attribute__((address_space(3))) void*)(As + 2048 + tid*8), 16, 0, 0);
    __builtin_amdgcn_global_load_lds(
        (const __attribute__((address_space(1))) void*)(bSrc0 + k0),
        (__attribute__((address_space(3))) void*)(Bs + tid*8), 16, 0, 0);
    __builtin_amdgcn_global_load_lds(
        (const __attribute__((address_space(1))) void*)(bSrc1 + k0),
        (__attribute__((address_space(3))) void*)(Bs + 2048 + tid*8), 16, 0, 0);
    __syncthreads();   // drains vmcnt: tiles resident
    // --- fragments + MFMA (BK=32 == one K step) ---
    half8 af[4], bf[4];
    #pragma unroll
    for (int i = 0; i < 4; i++)
      af[i] = *(const half8*)&As[(wm*64 + i*16 + lrow)*BK + lkq*8];
    #pragma unroll
    for (int j = 0; j < 4; j++)
      bf[j] = *(const half8*)&Bs[(wn*64 + j*16 + lrow)*BK + lkq*8];
    #pragma unroll
    for (int i = 0; i < 4; i++)
      #pragma unroll
      for (int j = 0; j < 4; j++)
        acc[i][j] = __builtin_amdgcn_mfma_f32_16x16x32_f16(af[i], bf[j], acc[i][j], 0, 0, 0);
  }

  // --- epilogue: add bias, packed half4 store into t-major plane p ---
  // P[p][b*256 + u][t], t = (m % 2048). r=0..3 of each acc reg are t-consecutive.
  const int p = bx >> 1;                // plane (z/r/h); BN=128 never crosses planes
  const int ub = (bx & 1) * 128;        // u base within plane
  const float* bias = (p==0) ? bz : ((p==1) ? br : bh);
  _Float16* Pp = P + (size_t)p * PLANE;
  const int bidx = rowBase >> 11;                 // batch index (uniform per block)
  const int t0 = (rowBase & 2047) + wm*64 + lkq*4;
  #pragma unroll
  for (int j = 0; j < 4; j++){
    int col = ub + wn*64 + j*16 + lrow;           // u  (C/D: col = lane&15)
    float bv = bias[col];
    _Float16* rowp = Pp + (size_t)(bidx*UU + col)*TT + t0;
    #pragma unroll
    for (int i = 0; i < 4; i++){
      half4 v;
      #pragma unroll
      for (int r = 0; r < 4; r++)
        v[r] = (_Float16)(acc[i][j][r] + bv);     // row = quad*4+reg => t0 + i*16 + r
      *(half4*)(rowp + i*16) = v;
    }
  }
}

// ---------------- kernel 2: time scan, one lane per (b,u), t-major P ----------------
// (round-0 version, measured ~88us: 256 waves = 1/CU; ILP-2 variant spilled its
// register ring to scratch (VGPR=60 < 96-reg ring) and idled half the CUs: 255us.)
#define PF 16          // timesteps per chunk
#define NBUF 4         // register ring depth (prefetch distance 3 chunks)
__global__ __launch_bounds__(64) void scan_kernel(const _Float16* __restrict__ P,
                                                  const float* __restrict__ mz,
                                                  const float* __restrict__ mr,
                                                  float* __restrict__ out){
  const int ci = blockIdx.x*64 + threadIdx.x;   // chain id: b*256+u
  const int b = ci >> 8;
  const int u = ci & 255;
  const half8* pz = (const half8*)(P + (size_t)ci*TT);
  const half8* pr = (const half8*)(P + PLANE + (size_t)ci*TT);
  const half8* ph = (const half8*)(P + 2*PLANE + (size_t)ci*TT);
  float* po = out + (size_t)b*(TT*UU) + u;
  const float vmz = mz[u], vmr = mr[u];
  float h = 0.0f;

  half8 qz[NBUF][2], qr[NBUF][2], qh[NBUF][2];

#define LOADC(buf, c) do { \
    qz[buf][0] = pz[(c)*2];   qz[buf][1] = pz[(c)*2+1]; \
    qr[buf][0] = pr[(c)*2];   qr[buf][1] = pr[(c)*2+1]; \
    qh[buf][0] = ph[(c)*2];   qh[buf][1] = ph[(c)*2+1]; \
  } while(0)

#define PROC(buf, c) do { \
    _Pragma("unroll") \
    for (int i = 0; i < PF; i++){ \
      float xz = (float)qz[buf][i>>3][i&7]; \
      float xr = (float)qr[buf][i>>3][i&7]; \
      float xh = (float)qh[buf][i>>3][i&7]; \
      float r  = ftanh(xr + h*vmr) + 1.0f; \
      float z  = fsigmoid(xz + h*vmz); \
      float hh = ftanh(xh + r*h); \
      h = (1.0f - z)*hh + z*h; \
      po[(size_t)((c)*PF + i)*UU] = h; \
    } \
    if ((c) + NBUF < NC) LOADC(buf, (c) + NBUF); \
  } while(0)

  const int NC = TT/PF;   // 128 chunks
  LOADC(0, 0); LOADC(1, 1); LOADC(2, 2); LOADC(3, 3);
  for (int c = 0; c < NC; c += NBUF){
    PROC(0, c);
    PROC(1, c+1);
    PROC(2, c+2);
    PROC(3, c+3);
  }
#undef LOADC
#undef PROC
}

extern "C" void kernel_launch(void* const* d_in, const int* in_sizes, int n_in,
                              void* d_out, int out_size, void* d_ws, size_t ws_size,
                              hipStream_t stream) {
  (void)in_sizes; (void)n_in; (void)out_size; (void)ws_size;
  const float* x  = (const float*)d_in[0];
  const float* kz = (const float*)d_in[1];
  const float* kr = (const float*)d_in[2];
  const float* kh = (const float*)d_in[3];
  const float* mz = (const float*)d_in[4];
  const float* mr = (const float*)d_in[5];
  const float* bz = (const float*)d_in[6];
  const float* br = (const float*)d_in[7];
  const float* bh = (const float*)d_in[8];
  float* out = (float*)d_out;

  // ws layout: [K16T: 768*256 f16 = 393216 B][P: 3 planes * 33554432 f16 = 201326592 B]
  _Float16* K16T = (_Float16*)d_ws;
  _Float16* P    = (_Float16*)((char*)d_ws + 393216);
  // X16 (67MB) lives in d_out (134MB): gemm reads it, then scan fully overwrites out.
  _Float16* X16  = (_Float16*)d_out;

  hipLaunchKernelGGL(xcvt_kernel, dim3(4096), dim3(256), 0, stream, x, X16);
  hipLaunchKernelGGL(prep_kernel, dim3(NN*DD/256), dim3(256), 0, stream, kz, kr, kh, K16T);
  hipLaunchKernelGGL(gemm_kernel, dim3(NN/BN, MM/BM), dim3(256), 0, stream,
                     X16, K16T, bz, br, bh, P);
  hipLaunchKernelGGL(scan_kernel, dim3(256), dim3(64), 0, stream, P, mz, mr, out);
}